// Round 5
// baseline (1328.865 us; speedup 1.0000x reference)
//
#include <hip/hip_runtime.h>

typedef _Float16 half_t;
typedef _Float16 half8 __attribute__((ext_vector_type(8)));
typedef float floatx4 __attribute__((ext_vector_type(4)));

#define NSEQ   256      // B*S
#define TLEN   128
#define EMBD   512
#define UNITSZ 512
#define GC     2048     // 4*UNITS
#define NTOK   32768    // NSEQ*TLEN
#define NCOL   4096     // 2 dirs * GC
#define KDIM   512

// workspace layout (bytes)
constexpr size_t OFF_EMB = 0;                    // emb_f16: 33,554,432; first 2MB reused as tagged hbuf32 after gemm
constexpr size_t OFF_WT  = 33554432;             // WcatT fp16 [4096][512] = 4,194,304
constexpr size_t OFF_UT  = OFF_WT + 4194304;     // UcatT fp16 [4096][512] = 4,194,304
constexpr size_t OFF_HB  = OFF_UT + 4194304;     // (old hbuf region, unused)
constexpr size_t OFF_CNT = OFF_HB + 1048576;     // (unused)
constexpr size_t OFF_MSK = OFF_CNT + 4096;       // mask bits: 256 * 2 u64 = 4096 B
constexpr size_t OFF_XW  = OFF_MSK + 4096;       // xW fp16 [32768][4096] = 268,435,456

__device__ inline float sigm(float x)  { return 1.0f / (1.0f + __expf(-x)); }
__device__ inline float tanhx(float x) { return 2.0f / (1.0f + __expf(-2.0f * x)) - 1.0f; }

// ---------------------------------------------------------------------------
// Tagged-h exchange (R5). hbuf32[dir][par][row 256][unit 512] dwords, each
// dword = (step_tag << 16) | h_fp16_bits. A 4B aligned store is atomic, so
// every dword is self-describing: producers store fire-and-forget (NO drain,
// NO flag); the consumer's data load IS the poll — check tag==t in-register
// and retry if stale. Parity double-buffer => visible tags in a buffer are
// {0, t-2, t}; "all == t" <=> hi16(umin(dwords)) == t (lo16 f16 bits only
// break ties within equal hi16, so the min's hi16 is exact).
// All exchange traffic is agent-scope sc0 sc1 (proven; R2 showed L2-scope
// leaks staleness on gfx950 — do not retry without a dedicated probe).
// ---------------------------------------------------------------------------
__device__ inline unsigned ld_probe(const unsigned* p) {
    unsigned v;
    asm volatile("global_load_dword %0, %1, off sc0 sc1\n\t"
                 "s_waitcnt vmcnt(0)" : "=v"(v) : "v"(p) : "memory");
    return v;
}

__device__ inline void st_tag(unsigned* p, unsigned v) {
    asm volatile("global_store_dword %0, %1, off sc0 sc1" :: "v"(p), "v"(v) : "memory");
}

// issue 16 dwordx4 tagged-h loads covering 8 kk (K=256) for this lane's
// frag rows; NO wait — caller fences with s_waitcnt vmcnt(0).
__device__ inline void hb_batch(const unsigned* p, uint4* d) {
    asm volatile(
        "global_load_dwordx4 %0, %16, off sc0 sc1\n\t"
        "global_load_dwordx4 %1, %16, off offset:16 sc0 sc1\n\t"
        "global_load_dwordx4 %2, %16, off offset:128 sc0 sc1\n\t"
        "global_load_dwordx4 %3, %16, off offset:144 sc0 sc1\n\t"
        "global_load_dwordx4 %4, %16, off offset:256 sc0 sc1\n\t"
        "global_load_dwordx4 %5, %16, off offset:272 sc0 sc1\n\t"
        "global_load_dwordx4 %6, %16, off offset:384 sc0 sc1\n\t"
        "global_load_dwordx4 %7, %16, off offset:400 sc0 sc1\n\t"
        "global_load_dwordx4 %8, %16, off offset:512 sc0 sc1\n\t"
        "global_load_dwordx4 %9, %16, off offset:528 sc0 sc1\n\t"
        "global_load_dwordx4 %10, %16, off offset:640 sc0 sc1\n\t"
        "global_load_dwordx4 %11, %16, off offset:656 sc0 sc1\n\t"
        "global_load_dwordx4 %12, %16, off offset:768 sc0 sc1\n\t"
        "global_load_dwordx4 %13, %16, off offset:784 sc0 sc1\n\t"
        "global_load_dwordx4 %14, %16, off offset:896 sc0 sc1\n\t"
        "global_load_dwordx4 %15, %16, off offset:912 sc0 sc1"
        : "=&v"(d[0]), "=&v"(d[1]), "=&v"(d[2]), "=&v"(d[3]),
          "=&v"(d[4]), "=&v"(d[5]), "=&v"(d[6]), "=&v"(d[7]),
          "=&v"(d[8]), "=&v"(d[9]), "=&v"(d[10]), "=&v"(d[11]),
          "=&v"(d[12]), "=&v"(d[13]), "=&v"(d[14]), "=&v"(d[15])
        : "v"(p) : "memory");
}

__device__ inline unsigned minscan16(const uint4* d) {
    unsigned m = 0xffffffffu;
#pragma unroll
    for (int i = 0; i < 16; ++i) {
        m = m < d[i].x ? m : d[i].x;
        m = m < d[i].y ? m : d[i].y;
        m = m < d[i].z ? m : d[i].z;
        m = m < d[i].w ? m : d[i].w;
    }
    return m;
}

__device__ inline half8 unpack8(const uint4& a, const uint4& b) {
    union { unsigned u[4]; half8 v; } c;
    c.u[0] = (a.x & 0xffffu) | (a.y << 16);
    c.u[1] = (a.z & 0xffffu) | (a.w << 16);
    c.u[2] = (b.x & 0xffffu) | (b.y << 16);
    c.u[3] = (b.z & 0xffffu) | (b.w << 16);
    return c.v;
}

// issue next-step xW prefetch (16 x 2B, immutable data, plain cached loads),
// NO wait — drained by the step-tail vmcnt(0) (keep HBM drains OFF the
// observe path: R4 regression).
__device__ inline void xv_issue(const half_t* p0, const half_t* p1,
                                const half_t* p2, const half_t* p3,
                                unsigned* xvr) {
    asm volatile(
        "global_load_ushort %0, %16, off\n\t"
        "global_load_ushort %1, %16, off offset:1024\n\t"
        "global_load_ushort %2, %16, off offset:2048\n\t"
        "global_load_ushort %3, %16, off offset:3072\n\t"
        "global_load_ushort %4, %17, off\n\t"
        "global_load_ushort %5, %17, off offset:1024\n\t"
        "global_load_ushort %6, %17, off offset:2048\n\t"
        "global_load_ushort %7, %17, off offset:3072\n\t"
        "global_load_ushort %8, %18, off\n\t"
        "global_load_ushort %9, %18, off offset:1024\n\t"
        "global_load_ushort %10, %18, off offset:2048\n\t"
        "global_load_ushort %11, %18, off offset:3072\n\t"
        "global_load_ushort %12, %19, off\n\t"
        "global_load_ushort %13, %19, off offset:1024\n\t"
        "global_load_ushort %14, %19, off offset:2048\n\t"
        "global_load_ushort %15, %19, off offset:3072"
        : "=&v"(xvr[0]), "=&v"(xvr[1]), "=&v"(xvr[2]), "=&v"(xvr[3]),
          "=&v"(xvr[4]), "=&v"(xvr[5]), "=&v"(xvr[6]), "=&v"(xvr[7]),
          "=&v"(xvr[8]), "=&v"(xvr[9]), "=&v"(xvr[10]), "=&v"(xvr[11]),
          "=&v"(xvr[12]), "=&v"(xvr[13]), "=&v"(xvr[14]), "=&v"(xvr[15])
        : "v"(p0), "v"(p1), "v"(p2), "v"(p3) : "memory");
}

// ---------------- pack W/U (fp32 [512][2048] per dir) -> transposed fp16 [dir*2048+gcol][512]
__global__ void pack_kernel(const float* __restrict__ Wf, const float* __restrict__ Uf,
                            const float* __restrict__ Wb, const float* __restrict__ Ub,
                            half_t* __restrict__ WT, half_t* __restrict__ UT) {
    int c = blockIdx.x * 256 + threadIdx.x;          // 524288 chunks total
    int arr = c >> 18;                               // 0 = W, 1 = U
    int r = c & 262143;                              // 262144 = 4096*64
    int kc = r >> 12;                                // 64 chunks of 8 k
    int gc = r & 4095;                               // lanes vary gc -> coalesced reads
    int dir = gc >> 11;
    int g = gc & 2047;
    const float* src = (arr == 0) ? (dir ? Wb : Wf) : (dir ? Ub : Uf);
    half_t* dst = (arr == 0) ? WT : UT;
    half8 v;
#pragma unroll
    for (int j = 0; j < 8; ++j)
        v[j] = (half_t)src[(size_t)(kc * 8 + j) * GC + g];
    *(half8*)(dst + (size_t)gc * KDIM + kc * 8) = v;
}

// ---------------- zero tagged hbuf32 (runs AFTER gemm; region aliases embf)
__global__ void zero32_kernel(unsigned* __restrict__ p) {
    p[blockIdx.x * 256 + threadIdx.x] = 0u;          // 524288 dwords = 2MB
}

// ---------------- pack per-row validity masks: mk[n] = 128 bits of (x!=0)
__global__ void mask_kernel(const int* __restrict__ x, unsigned long long* __restrict__ mk) {
    int n = blockIdx.x;       // 256 blocks x 64 threads
    int l = threadIdx.x;
    unsigned long long b0 = __ballot(x[n * TLEN + l] != 0);
    unsigned long long b1 = __ballot(x[n * TLEN + 64 + l] != 0);
    if (l == 0) { mk[n * 2] = b0; mk[n * 2 + 1] = b1; }
}

// ---------------- gather: emb_f16[token][512] = fp16(emb_table[x[token]][:])
__global__ void gather_kernel(const int* __restrict__ x, const float* __restrict__ tab,
                              half_t* __restrict__ embf) {
    int g = blockIdx.x * 256 + threadIdx.x;          // 2,097,152 chunks of 8
    int token = g >> 6;
    int k = (g & 63) * 8;
    int id = x[token];
    const float* s = tab + (size_t)id * EMBD + k;
    float4 a = *(const float4*)(s);
    float4 b = *(const float4*)(s + 4);
    half8 v;
    v[0] = (half_t)a.x; v[1] = (half_t)a.y; v[2] = (half_t)a.z; v[3] = (half_t)a.w;
    v[4] = (half_t)b.x; v[5] = (half_t)b.y; v[6] = (half_t)b.z; v[7] = (half_t)b.w;
    *(half8*)(embf + (size_t)token * EMBD + k) = v;
}

// ---------------- GEMM: xW[32768][4096] = emb_f16 @ WcatT^T + bias, fp16 out
__global__ __launch_bounds__(256, 2) void gemm_kernel(const half_t* __restrict__ embf,
                                                      const half_t* __restrict__ WT,
                                                      const float* __restrict__ bf,
                                                      const float* __restrict__ bb,
                                                      half_t* __restrict__ xw) {
    __shared__ half_t As[128 * 40];   // [row][32+8pad]
    __shared__ half_t Bs[128 * 40];   // B^T tile: [col][32+8pad]
    int bx = blockIdx.x;
    int bm = bx & 255, bn = bx >> 8;
    int r0 = bm * 128, c0 = bn * 128;
    int tid = threadIdx.x;
    int w = tid >> 6, l = tid & 63;
    int q = l >> 4, cl = l & 15;
    int mq = (w >> 1) * 64, nq = (w & 1) * 64;

    floatx4 acc[4][4];
#pragma unroll
    for (int a = 0; a < 4; ++a)
#pragma unroll
        for (int b = 0; b < 4; ++b) acc[a][b] = (floatx4){0.f, 0.f, 0.f, 0.f};

    for (int kb = 0; kb < 16; ++kb) {
#pragma unroll
        for (int cc = 0; cc < 2; ++cc) {
            int c = tid + cc * 256;
            int row = c >> 2, qt = c & 3;
            half8 va = *(const half8*)(embf + (size_t)(r0 + row) * KDIM + kb * 32 + qt * 8);
            *(half8*)(As + row * 40 + qt * 8) = va;
            half8 vb = *(const half8*)(WT + (size_t)(c0 + row) * KDIM + kb * 32 + qt * 8);
            *(half8*)(Bs + row * 40 + qt * 8) = vb;
        }
        __syncthreads();
        half8 af[4], bfr[4];
#pragma unroll
        for (int mb = 0; mb < 4; ++mb)
            af[mb] = *(const half8*)(As + (mq + mb * 16 + cl) * 40 + q * 8);
#pragma unroll
        for (int nb = 0; nb < 4; ++nb)
            bfr[nb] = *(const half8*)(Bs + (nq + nb * 16 + cl) * 40 + q * 8);
#pragma unroll
        for (int mb = 0; mb < 4; ++mb)
#pragma unroll
            for (int nb = 0; nb < 4; ++nb)
                acc[mb][nb] = __builtin_amdgcn_mfma_f32_16x16x32_f16(af[mb], bfr[nb], acc[mb][nb], 0, 0, 0);
        __syncthreads();
    }
    // epilogue: + bias, store fp16
#pragma unroll
    for (int nb = 0; nb < 4; ++nb) {
        int col = c0 + nq + nb * 16 + cl;
        int dir = col >> 11, gcol = col & 2047;
        float bias = dir ? bb[gcol] : bf[gcol];
#pragma unroll
        for (int mb = 0; mb < 4; ++mb) {
#pragma unroll
            for (int r = 0; r < 4; ++r) {
                int row = r0 + mq + mb * 16 + q * 4 + r;
                xw[(size_t)row * NCOL + col] = (half_t)(acc[mb][nb][r] + bias);
            }
        }
    }
}

// ---------------------------------------------------------------------------
// Persistent bidirectional LSTM, 256 blocks x 256 threads, tagged-h exchange:
//   per step (t>0): probe-spin (4B/lane, lanes spread over the 8 producer
//   blocks x 4 waves x 2 rows) -> batch0 (16 dwordx4, kk0-7) + min-tag check
//   (rare retry) -> unpack -> issue batch1 -> acc init -> MFMA kk0-7 ->
//   vmcnt(0) -> check/unpack batch1 -> MFMA kk8-15 -> gates -> 4 tagged
//   dword stores (fire-and-forget: the store IS the signal) -> xW prefetch
//   -> tail vmcnt(0) (drains stores + prefetch OFF the observe path).
//   No LDS, no __syncthreads, no atomics, no flags, no producer-side drain
//   before "signalling". All spins capped (fail measurably, never hang).
// ---------------------------------------------------------------------------
__global__ __launch_bounds__(256, 1) void lstm_kernel(const half_t* __restrict__ xw,
                                                      const half_t* __restrict__ UT,
                                                      unsigned* __restrict__ hb,
                                                      const unsigned long long* __restrict__ mk,
                                                      float* __restrict__ out) {
    int bx = blockIdx.x;
    int grp = bx & 31;              // group id (dir*16+rowg); members: bx = grp + 32*j
    int wgc = bx >> 5;              // member 0..7 = unit-column group
    int dir = grp >> 4;
    int rowg = grp & 15;
    int tid = threadIdx.x;
    int w = tid >> 6, l = tid & 63;
    int q = l >> 4, cl = l & 15;
    int cg = wgc * 4 + w;           // col-group 0..31
    int ub = cg * 16;               // unit base (per wave)
    int r0 = rowg * 16;             // sequence-row base

    // preload U B-frags into registers: bfrag[kk*4+cf], cf = gate (immutable, cached)
    half8 bfrag[64];
#pragma unroll
    for (int kk = 0; kk < 16; ++kk)
#pragma unroll
        for (int cf = 0; cf < 4; ++cf)
            bfrag[kk * 4 + cf] = *(const half8*)(UT + (size_t)(dir * 2048 + cf * 512 + ub + cl) * KDIM + kk * 32 + q * 8);

    // preload this thread's 4 rows' validity masks (128 bits each)
    unsigned long long mlo[4], mhi[4];
#pragma unroll
    for (int r = 0; r < 4; ++r) {
        int n = r0 + q * 4 + r;
        mlo[r] = mk[n * 2];
        mhi[r] = mk[n * 2 + 1];
    }

    float cs[4] = {0.f, 0.f, 0.f, 0.f};
    float hs[4] = {0.f, 0.f, 0.f, 0.f};
    int colb = dir * 2048 + ub + cl;

    // tagged hbuf pointers (dword layout [dir][par][row][unit])
    unsigned* hbd = hb + (size_t)(dir * 2) * NSEQ * UNITSZ;
    const unsigned* ap0 = hbd + (size_t)(r0 + cl) * UNITSZ + q * 8;          // par0 read base
    const unsigned* ap1 = ap0 + (size_t)NSEQ * UNITSZ;
    unsigned* hw0 = hbd + (size_t)(r0 + q * 4) * UNITSZ + ub + cl;           // par0 write base
    unsigned* hw1 = hw0 + (size_t)NSEQ * UNITSZ;
    // probe: lane l covers producer block jb, wave wwp, row rr
    int jb = l & 7, wwp = (l >> 3) & 3, rr = (l >> 5) * 8;
    const unsigned* pp0 = hbd + (size_t)(r0 + rr) * UNITSZ + jb * 64 + wwp * 16;
    const unsigned* pp1 = pp0 + (size_t)NSEQ * UNITSZ;

    // xW row bases for prefetch
    const half_t* xb0 = xw + (size_t)(r0 + q * 4 + 0) * TLEN * NCOL + colb;
    const half_t* xb1 = xw + (size_t)(r0 + q * 4 + 1) * TLEN * NCOL + colb;
    const half_t* xb2 = xw + (size_t)(r0 + q * 4 + 2) * TLEN * NCOL + colb;
    const half_t* xb3 = xw + (size_t)(r0 + q * 4 + 3) * TLEN * NCOL + colb;

    // prefetch xW for t=0 (bias already baked in)
    unsigned xvr[16];
    {
        int tI = dir ? 127 : 0;
        xv_issue(xb0 + (size_t)tI * NCOL, xb1 + (size_t)tI * NCOL,
                 xb2 + (size_t)tI * NCOL, xb3 + (size_t)tI * NCOL, xvr);
    }
    asm volatile("s_waitcnt vmcnt(0)" ::: "memory");
    __builtin_amdgcn_sched_barrier(0);

#pragma unroll 1
    for (int t = 0; t < TLEN; ++t) {
        int tIdx = dir ? (127 - t) : t;
        int rpar = t & 1;
        floatx4 a0, a1, a2, a3;
        if (t > 0) {
            unsigned tg = (unsigned)t;
            // ---- probe spin: 4B/lane, covers all producer blocks/waves
            const unsigned* pp = rpar ? pp1 : pp0;
            for (unsigned sp = 0;; ++sp) {
                unsigned pv = ld_probe(pp);
                if (__all((int)((pv >> 16) == tg))) break;
                if (sp >= (1u << 20)) break;            // hang-safety
                __builtin_amdgcn_s_sleep(1);
            }
            const unsigned* bp = rpar ? ap1 : ap0;
            // ---- batch0 (kk 0-7): load + full tag check (rare retry)
            uint4 d0[16];
            for (unsigned sp = 0;; ++sp) {
                hb_batch(bp, d0);
                asm volatile("s_waitcnt vmcnt(0)" ::: "memory");
                __builtin_amdgcn_sched_barrier(0);
                unsigned m = minscan16(d0);
                if (__all((int)((m >> 16) == tg))) break;
                if (sp >= 65536u) break;                // hang-safety
            }
            half8 af[16];
#pragma unroll
            for (int kk = 0; kk < 8; ++kk)
                af[kk] = unpack8(d0[2 * kk], d0[2 * kk + 1]);
            // ---- issue batch1 (kk 8-15); its RT hides under MFMA kk0-7
            uint4 d1[16];
            hb_batch(bp + 256, d1);
            // acc init from prefetched xW (drained by last step's tail vmcnt(0))
#pragma unroll
            for (int r = 0; r < 4; ++r) {
                a0[r] = (float)__builtin_bit_cast(half_t, (unsigned short)xvr[r * 4 + 0]);
                a1[r] = (float)__builtin_bit_cast(half_t, (unsigned short)xvr[r * 4 + 1]);
                a2[r] = (float)__builtin_bit_cast(half_t, (unsigned short)xvr[r * 4 + 2]);
                a3[r] = (float)__builtin_bit_cast(half_t, (unsigned short)xvr[r * 4 + 3]);
            }
#pragma unroll
            for (int kk = 0; kk < 8; ++kk) {
                a0 = __builtin_amdgcn_mfma_f32_16x16x32_f16(af[kk], bfrag[kk * 4 + 0], a0, 0, 0, 0);
                a1 = __builtin_amdgcn_mfma_f32_16x16x32_f16(af[kk], bfrag[kk * 4 + 1], a1, 0, 0, 0);
                a2 = __builtin_amdgcn_mfma_f32_16x16x32_f16(af[kk], bfrag[kk * 4 + 2], a2, 0, 0, 0);
                a3 = __builtin_amdgcn_mfma_f32_16x16x32_f16(af[kk], bfrag[kk * 4 + 3], a3, 0, 0, 0);
            }
            asm volatile("s_waitcnt vmcnt(0)" ::: "memory");
            __builtin_amdgcn_sched_barrier(0);
            // ---- batch1 check (first iteration checks already-loaded data)
            for (unsigned sp = 0;; ++sp) {
                unsigned m = minscan16(d1);
                if (__all((int)((m >> 16) == tg))) break;
                if (sp >= 65536u) break;                // hang-safety
                hb_batch(bp + 256, d1);
                asm volatile("s_waitcnt vmcnt(0)" ::: "memory");
                __builtin_amdgcn_sched_barrier(0);
            }
#pragma unroll
            for (int kk = 8; kk < 16; ++kk)
                af[kk] = unpack8(d1[2 * (kk - 8)], d1[2 * (kk - 8) + 1]);
#pragma unroll
            for (int kk = 8; kk < 16; ++kk) {
                a0 = __builtin_amdgcn_mfma_f32_16x16x32_f16(af[kk], bfrag[kk * 4 + 0], a0, 0, 0, 0);
                a1 = __builtin_amdgcn_mfma_f32_16x16x32_f16(af[kk], bfrag[kk * 4 + 1], a1, 0, 0, 0);
                a2 = __builtin_amdgcn_mfma_f32_16x16x32_f16(af[kk], bfrag[kk * 4 + 2], a2, 0, 0, 0);
                a3 = __builtin_amdgcn_mfma_f32_16x16x32_f16(af[kk], bfrag[kk * 4 + 3], a3, 0, 0, 0);
            }
        } else {
            // t=0: z = xW only (h = 0)
#pragma unroll
            for (int r = 0; r < 4; ++r) {
                a0[r] = (float)__builtin_bit_cast(half_t, (unsigned short)xvr[r * 4 + 0]);
                a1[r] = (float)__builtin_bit_cast(half_t, (unsigned short)xvr[r * 4 + 1]);
                a2[r] = (float)__builtin_bit_cast(half_t, (unsigned short)xvr[r * 4 + 2]);
                a3[r] = (float)__builtin_bit_cast(half_t, (unsigned short)xvr[r * 4 + 3]);
            }
        }
        // gates + masked state update; tagged h store (fire-and-forget)
        unsigned* hdst = rpar ? hw0 : hw1;
        unsigned tagv = ((unsigned)(t + 1)) << 16;
#pragma unroll
        for (int r = 0; r < 4; ++r) {
            unsigned long long mw = (tIdx & 64) ? mhi[r] : mlo[r];
            bool keep = (mw >> (tIdx & 63)) & 1ull;
            float iv = sigm(a0[r]);
            float fv = sigm(a1[r]);
            float gv = tanhx(a2[r]);
            float ov = sigm(a3[r]);
            float cn = fv * cs[r] + iv * gv;
            float hn = ov * tanhx(cn);
            if (keep) { cs[r] = cn; hs[r] = hn; }
            unsigned hv = tagv | (unsigned)__builtin_bit_cast(unsigned short, (half_t)hs[r]);
            st_tag(hdst + r * 512, hv);
        }
        // next-step xW prefetch, then tail drain (stores + prefetch) —
        // keeps the next step's observe path free of older VMEM ops.
        if (t + 1 < TLEN) {
            int tN = dir ? (126 - t) : (t + 1);
            xv_issue(xb0 + (size_t)tN * NCOL, xb1 + (size_t)tN * NCOL,
                     xb2 + (size_t)tN * NCOL, xb3 + (size_t)tN * NCOL, xvr);
        }
        asm volatile("s_waitcnt vmcnt(0)" ::: "memory");
        __builtin_amdgcn_sched_barrier(0);
    }
    // final output: out[n][dir*512 + unit]
#pragma unroll
    for (int r = 0; r < 4; ++r) {
        int n = r0 + q * 4 + r;
        out[(size_t)n * 1024 + dir * 512 + ub + cl] = hs[r];
    }
}

extern "C" void kernel_launch(void* const* d_in, const int* in_sizes, int n_in,
                              void* d_out, int out_size, void* d_ws, size_t ws_size,
                              hipStream_t stream) {
    const int*   x    = (const int*)d_in[0];
    const float* tab  = (const float*)d_in[1];
    const float* Wf   = (const float*)d_in[2];
    const float* Uf   = (const float*)d_in[3];
    const float* bf   = (const float*)d_in[4];
    const float* Wb   = (const float*)d_in[5];
    const float* Ub   = (const float*)d_in[6];
    const float* bb   = (const float*)d_in[7];
    float* out = (float*)d_out;

    char* ws = (char*)d_ws;
    half_t*   embf = (half_t*)(ws + OFF_EMB);
    half_t*   WT   = (half_t*)(ws + OFF_WT);
    half_t*   UT   = (half_t*)(ws + OFF_UT);
    unsigned* hb32 = (unsigned*)(ws + OFF_EMB);  // tagged hbuf reuses dead emb region
    unsigned long long* mkb = (unsigned long long*)(ws + OFF_MSK);
    half_t*   xw   = (half_t*)(ws + OFF_XW);

    pack_kernel<<<2048, 256, 0, stream>>>(Wf, Uf, Wb, Ub, WT, UT);
    mask_kernel<<<256, 64, 0, stream>>>(x, mkb);
    gather_kernel<<<8192, 256, 0, stream>>>(x, tab, embf);
    gemm_kernel<<<8192, 256, 0, stream>>>(embf, WT, bf, bb, xw);
    zero32_kernel<<<2048, 256, 0, stream>>>(hb32);
    lstm_kernel<<<256, 256, 0, stream>>>(xw, UT, hb32, mkb, out);
}

// Round 7
// 1001.537 us; speedup vs baseline: 1.3268x; 1.3268x over previous
//
#include <hip/hip_runtime.h>

typedef _Float16 half_t;
typedef _Float16 half8 __attribute__((ext_vector_type(8)));
typedef float floatx4 __attribute__((ext_vector_type(4)));

#define NSEQ   256      // B*S
#define TLEN   128
#define EMBD   512
#define UNITSZ 512
#define GC     2048     // 4*UNITS
#define NTOK   32768    // NSEQ*TLEN
#define NCOL   4096     // 2 dirs * GC
#define KDIM   512

// workspace layout (bytes)
constexpr size_t OFF_EMB = 0;                    // emb_f16 32MB; first 16KB reused as flags after gemm
constexpr size_t OFF_WT  = 33554432;             // WcatT fp16 [4096][512] = 4,194,304
constexpr size_t OFF_UT  = OFF_WT + 4194304;     // UcatT fp16 [4096][512] = 4,194,304
constexpr size_t OFF_HB  = OFF_UT + 4194304;     // hbuf fp16 [2dir][2par][256][512] = 1,048,576
constexpr size_t OFF_CNT = OFF_HB + 1048576;     // (unused in R7)
constexpr size_t OFF_MSK = OFF_CNT + 4096;       // mask bits: 256 * 2 u64 = 4096 B
constexpr size_t OFF_XW  = OFF_MSK + 4096;       // xW fp16 [32768][4096] = 268,435,456

__device__ inline float sigm(float x)  { return 1.0f / (1.0f + __expf(-x)); }
__device__ inline float tanhx(float x) { return 2.0f / (1.0f + __expf(-2.0f * x)) - 1.0f; }

// ---------------------------------------------------------------------------
// Cross-block exchange — PROVEN agent-scope semantics only (sc0 sc1: bypass
// CU-L1 and XCD-L2; IF$/memory is the coherence point). R2/R6 lessons:
//  - L2-scope (sc0-only) exchange leaks staleness on gfx950: do not retry.
//  - Never keep more asm-output loads in flight than fit in registers:
//    a spilled in-flight output saves GARBAGE (R6 failure).
// Signalling (R7): per-producer-BLOCK single-writer flags on separate 64B
// lines. Producer: h stores -> vmcnt(0) (own-wave drain) -> __syncthreads
// (all 4 waves drained) -> ONE plain flag store (no RMW, single writer).
// Consumer: one lane-parallel load of the 8 flags (8 distinct lines).
// Removes R0/R3's 32 same-line atomic RMWs/step and R4's flag-line
// ping-pong (32 writers + 32 pollers on one 128B line).
// ---------------------------------------------------------------------------
__device__ inline unsigned ld_flag(const unsigned* p) {
    unsigned v;
    asm volatile("global_load_dword %0, %1, off sc0 sc1\n\t"
                 "s_waitcnt vmcnt(0)" : "=v"(v) : "v"(p) : "memory");
    return v;
}

__device__ inline void st_flag(unsigned* p, unsigned v) {
    asm volatile("global_store_dword %0, %1, off sc0 sc1" :: "v"(p), "v"(v) : "memory");
}

__device__ inline void st_h(unsigned short* p, unsigned v) {
    asm volatile("global_store_short %0, %1, off sc0 sc1" :: "v"(p), "v"(v) : "memory");
}

// issue 16x16B A-fragment loads (one K-step each), NO wait — caller fences
// with s_waitcnt vmcnt(0) after overlapping VALU work. 64 VGPRs in flight:
// fits (R3 proven, VGPR=216).
__device__ inline void af_issue(const half_t* ap, half8* af) {
    asm volatile(
        "global_load_dwordx4 %0, %16, off sc0 sc1\n\t"
        "global_load_dwordx4 %1, %16, off offset:64 sc0 sc1\n\t"
        "global_load_dwordx4 %2, %16, off offset:128 sc0 sc1\n\t"
        "global_load_dwordx4 %3, %16, off offset:192 sc0 sc1\n\t"
        "global_load_dwordx4 %4, %16, off offset:256 sc0 sc1\n\t"
        "global_load_dwordx4 %5, %16, off offset:320 sc0 sc1\n\t"
        "global_load_dwordx4 %6, %16, off offset:384 sc0 sc1\n\t"
        "global_load_dwordx4 %7, %16, off offset:448 sc0 sc1\n\t"
        "global_load_dwordx4 %8, %16, off offset:512 sc0 sc1\n\t"
        "global_load_dwordx4 %9, %16, off offset:576 sc0 sc1\n\t"
        "global_load_dwordx4 %10, %16, off offset:640 sc0 sc1\n\t"
        "global_load_dwordx4 %11, %16, off offset:704 sc0 sc1\n\t"
        "global_load_dwordx4 %12, %16, off offset:768 sc0 sc1\n\t"
        "global_load_dwordx4 %13, %16, off offset:832 sc0 sc1\n\t"
        "global_load_dwordx4 %14, %16, off offset:896 sc0 sc1\n\t"
        "global_load_dwordx4 %15, %16, off offset:960 sc0 sc1"
        : "=&v"(af[0]), "=&v"(af[1]), "=&v"(af[2]), "=&v"(af[3]),
          "=&v"(af[4]), "=&v"(af[5]), "=&v"(af[6]), "=&v"(af[7]),
          "=&v"(af[8]), "=&v"(af[9]), "=&v"(af[10]), "=&v"(af[11]),
          "=&v"(af[12]), "=&v"(af[13]), "=&v"(af[14]), "=&v"(af[15])
        : "v"(ap) : "memory");
}

// issue next-step xW prefetch (16 x 2B, immutable data, plain cached loads),
// NO wait — issued AFTER the flag store; lazily drained by the next step's
// first poll vmcnt(0) (overlaps the straggler wait).
__device__ inline void xv_issue(const half_t* p0, const half_t* p1,
                                const half_t* p2, const half_t* p3,
                                unsigned* xvr) {
    asm volatile(
        "global_load_ushort %0, %16, off\n\t"
        "global_load_ushort %1, %16, off offset:1024\n\t"
        "global_load_ushort %2, %16, off offset:2048\n\t"
        "global_load_ushort %3, %16, off offset:3072\n\t"
        "global_load_ushort %4, %17, off\n\t"
        "global_load_ushort %5, %17, off offset:1024\n\t"
        "global_load_ushort %6, %17, off offset:2048\n\t"
        "global_load_ushort %7, %17, off offset:3072\n\t"
        "global_load_ushort %8, %18, off\n\t"
        "global_load_ushort %9, %18, off offset:1024\n\t"
        "global_load_ushort %10, %18, off offset:2048\n\t"
        "global_load_ushort %11, %18, off offset:3072\n\t"
        "global_load_ushort %12, %19, off\n\t"
        "global_load_ushort %13, %19, off offset:1024\n\t"
        "global_load_ushort %14, %19, off offset:2048\n\t"
        "global_load_ushort %15, %19, off offset:3072"
        : "=&v"(xvr[0]), "=&v"(xvr[1]), "=&v"(xvr[2]), "=&v"(xvr[3]),
          "=&v"(xvr[4]), "=&v"(xvr[5]), "=&v"(xvr[6]), "=&v"(xvr[7]),
          "=&v"(xvr[8]), "=&v"(xvr[9]), "=&v"(xvr[10]), "=&v"(xvr[11]),
          "=&v"(xvr[12]), "=&v"(xvr[13]), "=&v"(xvr[14]), "=&v"(xvr[15])
        : "v"(p0), "v"(p1), "v"(p2), "v"(p3) : "memory");
}

// ---------------- pack W/U (fp32 [512][2048] per dir) -> transposed fp16 [dir*2048+gcol][512]
__global__ void pack_kernel(const float* __restrict__ Wf, const float* __restrict__ Uf,
                            const float* __restrict__ Wb, const float* __restrict__ Ub,
                            half_t* __restrict__ WT, half_t* __restrict__ UT) {
    int c = blockIdx.x * 256 + threadIdx.x;          // 524288 chunks total
    int arr = c >> 18;                               // 0 = W, 1 = U
    int r = c & 262143;                              // 262144 = 4096*64
    int kc = r >> 12;                                // 64 chunks of 8 k
    int gc = r & 4095;                               // lanes vary gc -> coalesced reads
    int dir = gc >> 11;
    int g = gc & 2047;
    const float* src = (arr == 0) ? (dir ? Wb : Wf) : (dir ? Ub : Uf);
    half_t* dst = (arr == 0) ? WT : UT;
    half8 v;
#pragma unroll
    for (int j = 0; j < 8; ++j)
        v[j] = (half_t)src[(size_t)(kc * 8 + j) * GC + g];
    *(half8*)(dst + (size_t)gc * KDIM + kc * 8) = v;
}

// ---------------- zero hbuf (plain stores; end-of-dispatch flush publishes)
__global__ void zero_kernel(unsigned* __restrict__ hb) {
    hb[blockIdx.x * 256 + threadIdx.x] = 0u;         // 262144 dwords = 1MB
}

// ---------------- zero flags (runs AFTER gemm; region aliases dead embf)
__global__ void zeroflg_kernel(unsigned* __restrict__ p) {
    p[blockIdx.x * 256 + threadIdx.x] = 0u;          // 4096 dwords = 16KB
}

// ---------------- pack per-row validity masks: mk[n] = 128 bits of (x!=0)
__global__ void mask_kernel(const int* __restrict__ x, unsigned long long* __restrict__ mk) {
    int n = blockIdx.x;       // 256 blocks x 64 threads
    int l = threadIdx.x;
    unsigned long long b0 = __ballot(x[n * TLEN + l] != 0);
    unsigned long long b1 = __ballot(x[n * TLEN + 64 + l] != 0);
    if (l == 0) { mk[n * 2] = b0; mk[n * 2 + 1] = b1; }
}

// ---------------- gather: emb_f16[token][512] = fp16(emb_table[x[token]][:])
__global__ void gather_kernel(const int* __restrict__ x, const float* __restrict__ tab,
                              half_t* __restrict__ embf) {
    int g = blockIdx.x * 256 + threadIdx.x;          // 2,097,152 chunks of 8
    int token = g >> 6;
    int k = (g & 63) * 8;
    int id = x[token];
    const float* s = tab + (size_t)id * EMBD + k;
    float4 a = *(const float4*)(s);
    float4 b = *(const float4*)(s + 4);
    half8 v;
    v[0] = (half_t)a.x; v[1] = (half_t)a.y; v[2] = (half_t)a.z; v[3] = (half_t)a.w;
    v[4] = (half_t)b.x; v[5] = (half_t)b.y; v[6] = (half_t)b.z; v[7] = (half_t)b.w;
    *(half8*)(embf + (size_t)token * EMBD + k) = v;
}

// ---------------- GEMM: xW[32768][4096] = emb_f16 @ WcatT^T + bias, fp16 out
__global__ __launch_bounds__(256, 2) void gemm_kernel(const half_t* __restrict__ embf,
                                                      const half_t* __restrict__ WT,
                                                      const float* __restrict__ bf,
                                                      const float* __restrict__ bb,
                                                      half_t* __restrict__ xw) {
    __shared__ half_t As[128 * 40];   // [row][32+8pad]
    __shared__ half_t Bs[128 * 40];   // B^T tile: [col][32+8pad]
    int bx = blockIdx.x;
    int bm = bx & 255, bn = bx >> 8;
    int r0 = bm * 128, c0 = bn * 128;
    int tid = threadIdx.x;
    int w = tid >> 6, l = tid & 63;
    int q = l >> 4, cl = l & 15;
    int mq = (w >> 1) * 64, nq = (w & 1) * 64;

    floatx4 acc[4][4];
#pragma unroll
    for (int a = 0; a < 4; ++a)
#pragma unroll
        for (int b = 0; b < 4; ++b) acc[a][b] = (floatx4){0.f, 0.f, 0.f, 0.f};

    for (int kb = 0; kb < 16; ++kb) {
#pragma unroll
        for (int cc = 0; cc < 2; ++cc) {
            int c = tid + cc * 256;
            int row = c >> 2, qt = c & 3;
            half8 va = *(const half8*)(embf + (size_t)(r0 + row) * KDIM + kb * 32 + qt * 8);
            *(half8*)(As + row * 40 + qt * 8) = va;
            half8 vb = *(const half8*)(WT + (size_t)(c0 + row) * KDIM + kb * 32 + qt * 8);
            *(half8*)(Bs + row * 40 + qt * 8) = vb;
        }
        __syncthreads();
        half8 af[4], bfr[4];
#pragma unroll
        for (int mb = 0; mb < 4; ++mb)
            af[mb] = *(const half8*)(As + (mq + mb * 16 + cl) * 40 + q * 8);
#pragma unroll
        for (int nb = 0; nb < 4; ++nb)
            bfr[nb] = *(const half8*)(Bs + (nq + nb * 16 + cl) * 40 + q * 8);
#pragma unroll
        for (int mb = 0; mb < 4; ++mb)
#pragma unroll
            for (int nb = 0; nb < 4; ++nb)
                acc[mb][nb] = __builtin_amdgcn_mfma_f32_16x16x32_f16(af[mb], bfr[nb], acc[mb][nb], 0, 0, 0);
        __syncthreads();
    }
    // epilogue: + bias, store fp16
#pragma unroll
    for (int nb = 0; nb < 4; ++nb) {
        int col = c0 + nq + nb * 16 + cl;
        int dir = col >> 11, gcol = col & 2047;
        float bias = dir ? bb[gcol] : bf[gcol];
#pragma unroll
        for (int mb = 0; mb < 4; ++mb) {
#pragma unroll
            for (int r = 0; r < 4; ++r) {
                int row = r0 + mq + mb * 16 + q * 4 + r;
                xw[(size_t)row * NCOL + col] = (half_t)(acc[mb][nb][r] + bias);
            }
        }
    }
}

// ---------------------------------------------------------------------------
// Persistent bidirectional LSTM, 256 blocks x 256 threads, agent-scope h
// exchange (R3-proven), single-writer block-flag signalling (R7):
//   per step (t>0): poll 8 block-flags (one lane-parallel load, 8 distinct
//   64B lines) -> af_issue (16x16B h loads) -> acc init under load shadow ->
//   vmcnt(0) -> MFMA x64 -> gates -> 4x st_h -> vmcnt(0) (own-wave h drain)
//   -> __syncthreads (all 4 waves drained) -> tid0: flag := t+1 (plain
//   single-writer store, fire-and-forget) -> xW prefetch (lazy-drained by
//   next poll's vmcnt(0)).
//   No LDS, no atomics, no RMW serialization, no flag-line sharing.
//   All spins capped: a protocol bug fails measurably, never hangs.
// ---------------------------------------------------------------------------
__global__ __launch_bounds__(256, 1) void lstm_kernel(const half_t* __restrict__ xw,
                                                      const half_t* __restrict__ UT,
                                                      half_t* __restrict__ hbuf,
                                                      const unsigned long long* __restrict__ mk,
                                                      float* __restrict__ out,
                                                      unsigned* __restrict__ flg) {
    int bx = blockIdx.x;
    int grp = bx & 31;              // group id (dir*16+rowg); members: bx = grp + 32*j
    int wgc = bx >> 5;              // member 0..7 = unit-column group
    int dir = grp >> 4;
    int rowg = grp & 15;
    int tid = threadIdx.x;
    int w = tid >> 6, l = tid & 63;
    int q = l >> 4, cl = l & 15;
    int cg = wgc * 4 + w;           // col-group 0..31
    int ub = cg * 16;               // unit base (per wave)
    int r0 = rowg * 16;             // sequence-row base

    // preload U B-frags into registers: bfrag[kk*4+cf], cf = gate (immutable, cached)
    half8 bfrag[64];
#pragma unroll
    for (int kk = 0; kk < 16; ++kk)
#pragma unroll
        for (int cf = 0; cf < 4; ++cf)
            bfrag[kk * 4 + cf] = *(const half8*)(UT + (size_t)(dir * 2048 + cf * 512 + ub + cl) * KDIM + kk * 32 + q * 8);

    // preload this thread's 4 rows' validity masks (128 bits each)
    unsigned long long mlo[4], mhi[4];
#pragma unroll
    for (int r = 0; r < 4; ++r) {
        int n = r0 + q * 4 + r;
        mlo[r] = mk[n * 2];
        mhi[r] = mk[n * 2 + 1];
    }

    float cs[4] = {0.f, 0.f, 0.f, 0.f};
    float hs[4] = {0.f, 0.f, 0.f, 0.f};
    int colb = dir * 2048 + ub + cl;

    // flags: one dword per (grp, producer-block), 64B apart. Poll: lane l
    // reads flag of producer block (l&7); producers never share a line.
    unsigned* myflag = flg + (grp * 8 + wgc) * 16;
    const unsigned* fpoll = flg + (grp * 8 + (l & 7)) * 16;

    // per-thread hbuf pointers (A-frag read is 16B contiguous per lane)
    const half_t* ap0 = hbuf + (size_t)(dir * 2 + 0) * NSEQ * UNITSZ + (size_t)(r0 + cl) * UNITSZ + q * 8;
    const half_t* ap1 = ap0 + (size_t)NSEQ * UNITSZ;
    half_t* hw0 = hbuf + (size_t)(dir * 2 + 0) * NSEQ * UNITSZ + (size_t)(r0 + q * 4) * UNITSZ + ub + cl;
    half_t* hw1 = hw0 + (size_t)NSEQ * UNITSZ;

    // xW row bases for prefetch
    const half_t* xb0 = xw + (size_t)(r0 + q * 4 + 0) * TLEN * NCOL + colb;
    const half_t* xb1 = xw + (size_t)(r0 + q * 4 + 1) * TLEN * NCOL + colb;
    const half_t* xb2 = xw + (size_t)(r0 + q * 4 + 2) * TLEN * NCOL + colb;
    const half_t* xb3 = xw + (size_t)(r0 + q * 4 + 3) * TLEN * NCOL + colb;

    // prefetch xW for t=0 (bias already baked in)
    unsigned xvr[16];
    {
        int tI = dir ? 127 : 0;
        xv_issue(xb0 + (size_t)tI * NCOL, xb1 + (size_t)tI * NCOL,
                 xb2 + (size_t)tI * NCOL, xb3 + (size_t)tI * NCOL, xvr);
    }
    asm volatile("s_waitcnt vmcnt(0)" ::: "memory");
    __builtin_amdgcn_sched_barrier(0);

#pragma unroll 1
    for (int t = 0; t < TLEN; ++t) {
        int tIdx = dir ? (127 - t) : t;
        int rpar = t & 1;
        floatx4 a0, a1, a2, a3;
        half8 af[16];
        if (t > 0) {
            // wait until all 8 producer blocks have published h(t-1):
            // flag value >= t (stored as t at end of step t-1).
            unsigned tgt = (unsigned)t;
            for (unsigned sp = 0;; ++sp) {
                unsigned v = ld_flag(fpoll);   // vmcnt(0): also drains xW prefetch
                if (__all((int)(v >= tgt))) break;
                if (sp >= (1u << 20)) break;   // hang-safety: fail measurably
                __builtin_amdgcn_s_sleep(1);
            }
            __builtin_amdgcn_sched_barrier(0);
            af_issue(rpar ? ap1 : ap0, af);    // 16 loads, wait below
        }
        // acc init from prefetched xW under the af-load shadow
        // (xvr drained: t=0 by preloop vmcnt(0), t>0 by the poll's vmcnt(0))
#pragma unroll
        for (int r = 0; r < 4; ++r) {
            a0[r] = (float)__builtin_bit_cast(half_t, (unsigned short)xvr[r * 4 + 0]);
            a1[r] = (float)__builtin_bit_cast(half_t, (unsigned short)xvr[r * 4 + 1]);
            a2[r] = (float)__builtin_bit_cast(half_t, (unsigned short)xvr[r * 4 + 2]);
            a3[r] = (float)__builtin_bit_cast(half_t, (unsigned short)xvr[r * 4 + 3]);
        }
        if (t > 0) {
            asm volatile("s_waitcnt vmcnt(0)" ::: "memory");   // af loads landed
            __builtin_amdgcn_sched_barrier(0);
#pragma unroll
            for (int kk = 0; kk < 16; ++kk) {
                a0 = __builtin_amdgcn_mfma_f32_16x16x32_f16(af[kk], bfrag[kk * 4 + 0], a0, 0, 0, 0);
                a1 = __builtin_amdgcn_mfma_f32_16x16x32_f16(af[kk], bfrag[kk * 4 + 1], a1, 0, 0, 0);
                a2 = __builtin_amdgcn_mfma_f32_16x16x32_f16(af[kk], bfrag[kk * 4 + 2], a2, 0, 0, 0);
                a3 = __builtin_amdgcn_mfma_f32_16x16x32_f16(af[kk], bfrag[kk * 4 + 3], a3, 0, 0, 0);
            }
        }
        // gates + masked state update (mask from registers), direct h store
        unsigned short* hdst = (unsigned short*)(rpar ? hw0 : hw1);
#pragma unroll
        for (int r = 0; r < 4; ++r) {
            unsigned long long mw = (tIdx & 64) ? mhi[r] : mlo[r];
            bool keep = (mw >> (tIdx & 63)) & 1ull;
            float iv = sigm(a0[r]);
            float fv = sigm(a1[r]);
            float gv = tanhx(a2[r]);
            float ov = sigm(a3[r]);
            float cn = fv * cs[r] + iv * gv;
            float hn = ov * tanhx(cn);
            if (keep) { cs[r] = cn; hs[r] = hn; }
            unsigned hv = (unsigned)__builtin_bit_cast(unsigned short, (half_t)hs[r]);
            st_h(hdst + r * 512, hv);
        }
        // drain ONLY this wave's 4 h-stores (nothing else outstanding)
        asm volatile("s_waitcnt vmcnt(0)" ::: "memory");
        __builtin_amdgcn_sched_barrier(0);
        // intra-block rendezvous: all 4 waves' h at the coherence point
        __syncthreads();
        // single-writer release flag (no RMW; data already drained by all)
        if (tid == 0)
            st_flag(myflag, (unsigned)(t + 1));
        // next-step xW prefetch — lazy-drained by the next poll's vmcnt(0),
        // overlapping the straggler wait.
        if (t + 1 < TLEN) {
            int tN = dir ? (126 - t) : (t + 1);
            xv_issue(xb0 + (size_t)tN * NCOL, xb1 + (size_t)tN * NCOL,
                     xb2 + (size_t)tN * NCOL, xb3 + (size_t)tN * NCOL, xvr);
        }
    }
    // final output: out[n][dir*512 + unit]
#pragma unroll
    for (int r = 0; r < 4; ++r) {
        int n = r0 + q * 4 + r;
        out[(size_t)n * 1024 + dir * 512 + ub + cl] = hs[r];
    }
}

extern "C" void kernel_launch(void* const* d_in, const int* in_sizes, int n_in,
                              void* d_out, int out_size, void* d_ws, size_t ws_size,
                              hipStream_t stream) {
    const int*   x    = (const int*)d_in[0];
    const float* tab  = (const float*)d_in[1];
    const float* Wf   = (const float*)d_in[2];
    const float* Uf   = (const float*)d_in[3];
    const float* bf   = (const float*)d_in[4];
    const float* Wb   = (const float*)d_in[5];
    const float* Ub   = (const float*)d_in[6];
    const float* bb   = (const float*)d_in[7];
    float* out = (float*)d_out;

    char* ws = (char*)d_ws;
    half_t*   embf = (half_t*)(ws + OFF_EMB);
    half_t*   WT   = (half_t*)(ws + OFF_WT);
    half_t*   UT   = (half_t*)(ws + OFF_UT);
    half_t*   hbuf = (half_t*)(ws + OFF_HB);
    unsigned long long* mkb = (unsigned long long*)(ws + OFF_MSK);
    half_t*   xw   = (half_t*)(ws + OFF_XW);
    unsigned* hbz  = (unsigned*)(ws + OFF_HB);
    unsigned* flg  = (unsigned*)(ws + OFF_EMB);  // flags reuse dead emb region (16KB)

    pack_kernel<<<2048, 256, 0, stream>>>(Wf, Uf, Wb, Ub, WT, UT);
    zero_kernel<<<1024, 256, 0, stream>>>(hbz);
    mask_kernel<<<256, 64, 0, stream>>>(x, mkb);
    gather_kernel<<<8192, 256, 0, stream>>>(x, tab, embf);
    gemm_kernel<<<8192, 256, 0, stream>>>(embf, WT, bf, bb, xw);
    zeroflg_kernel<<<16, 256, 0, stream>>>(flg);
    lstm_kernel<<<256, 256, 0, stream>>>(xw, UT, hbuf, mkb, out, flg);
}